// Round 1
// 4258.769 us; speedup vs baseline: 1.2770x; 1.2770x over previous
//
#include <hip/hip_runtime.h>
#include <stdint.h>

#define B_  128
#define T_  512
#define H_  512
#define G3  1536

typedef __attribute__((ext_vector_type(8))) short bf16x8;
typedef __attribute__((ext_vector_type(4))) short bf16x4;
typedef __attribute__((ext_vector_type(4))) float f32x4;
typedef __attribute__((ext_vector_type(4))) int   int4v;

#define MFMA16(a,b,c) __builtin_amdgcn_mfma_f32_16x16x32_bf16((a),(b),(c),0,0,0)

__device__ __forceinline__ unsigned short f2bf(float f) {
  union { float f; unsigned u; } v; v.f = f;
  unsigned r = v.u + 0x7FFFu + ((v.u >> 16) & 1u);
  return (unsigned short)(r >> 16);
}
__device__ __forceinline__ float bf2f(unsigned short u) {
  union { unsigned u; float f; } v; v.u = ((unsigned)u) << 16; return v.f;
}
__device__ __forceinline__ float sigm_f(float x) { return 1.f / (1.f + __expf(-x)); }
__device__ __forceinline__ float tanh_f(float x) { float e = __expf(2.f * x); return 1.f - 2.f / (e + 1.f); }

// ---- scoped memory helpers -------------------------------------------------
// CLEAN (all 16 group blocks verified on ONE XCD): plain write-through stores
// + sc0 (L1-bypass) loads -> coherence point is the XCD's own L2 (~250 cy).
// !CLEAN fallback: sc0 sc1 on everything -> coherence at MALL (~1000 cy),
// correct for any block->XCD placement (same semantics as agent atomics).
template<bool CLEAN>
__device__ __forceinline__ void ldh16(int4v& d, const unsigned short* p) {
  if constexpr (CLEAN)
    asm volatile("global_load_dwordx4 %0, %1, off sc0" : "=v"(d) : "v"(p));
  else
    asm volatile("global_load_dwordx4 %0, %1, off sc0 sc1" : "=v"(d) : "v"(p));
}
template<bool CLEAN>
__device__ __forceinline__ void sth64(unsigned short* p, unsigned long long v) {
  if constexpr (CLEAN)
    asm volatile("global_store_dwordx2 %0, %1, off" :: "v"(p), "v"(v) : "memory");
  else
    asm volatile("global_store_dwordx2 %0, %1, off sc0 sc1" :: "v"(p), "v"(v) : "memory");
}
template<bool CLEAN>
__device__ __forceinline__ unsigned ldflag(const unsigned* p) {
  unsigned v;
  if constexpr (CLEAN)
    asm volatile("global_load_dword %0, %1, off sc0\n\ts_waitcnt vmcnt(0)"
                 : "=v"(v) : "v"(p) : "memory");
  else
    asm volatile("global_load_dword %0, %1, off sc0 sc1\n\ts_waitcnt vmcnt(0)"
                 : "=v"(v) : "v"(p) : "memory");
  return v;
}
template<bool CLEAN>
__device__ __forceinline__ void stflag(unsigned* p) {
  unsigned one = 1u;
  if constexpr (CLEAN)
    asm volatile("global_store_dword %0, %1, off" :: "v"(p), "v"(one) : "memory");
  else
    asm volatile("global_store_dword %0, %1, off sc0 sc1" :: "v"(p), "v"(one) : "memory");
}

// ---------------- K0: cast weights to bf16 + zero barrier flags ----------------
__launch_bounds__(256)
__global__ void k_cast(const float* __restrict__ Wih_f, const float* __restrict__ Wih_b,
                       const float* __restrict__ Whh_f, const float* __restrict__ Whh_b,
                       const float* __restrict__ Wp,
                       unsigned short* __restrict__ Wih, unsigned short* __restrict__ Whh,
                       unsigned short* __restrict__ Wpb, unsigned* __restrict__ flags) {
  int idx = blockIdx.x * 256 + threadIdx.x;
  if (idx < 65536) flags[idx] = 0;          // [8 grp][512 t][16 slot] flags + claim ctrs
  if (idx < 1572864) {            // Wih: [2][1536][512]
    float v = (idx < 786432) ? Wih_f[idx] : Wih_b[idx - 786432];
    Wih[idx] = f2bf(v);
  } else if (idx < 3145728) {     // Whh: [2][1536][512]
    int i2 = idx - 1572864;
    float v = (i2 < 786432) ? Whh_f[i2] : Whh_b[i2 - 786432];
    Whh[i2] = f2bf(v);
  } else if (idx < 3670016) {     // Wp: [512][1024]
    int i3 = idx - 3145728;
    Wpb[i3] = f2bf(Wp[i3]);
  }
}

// ---------------- K1: gather embedding -> x_bf [65536][512] ----------------
__launch_bounds__(256)
__global__ void k_gather(const int* __restrict__ tokens, const float* __restrict__ emb,
                         unsigned short* __restrict__ xbf) {
  int row = blockIdx.x * 4 + (threadIdx.x >> 6);
  int lane = threadIdx.x & 63;
  int tok = tokens[row];
  const float4* src = (const float4*)(emb + (size_t)tok * 512);
  float4 v0 = src[lane * 2], v1 = src[lane * 2 + 1];
  bf16x8 pk;
  pk[0] = (short)f2bf(v0.x); pk[1] = (short)f2bf(v0.y);
  pk[2] = (short)f2bf(v0.z); pk[3] = (short)f2bf(v0.w);
  pk[4] = (short)f2bf(v1.x); pk[5] = (short)f2bf(v1.y);
  pk[6] = (short)f2bf(v1.z); pk[7] = (short)f2bf(v1.w);
  *(bf16x8*)&xbf[(size_t)row * 512 + lane * 8] = pk;
}

// ---------------- K2: persistent bidirectional GRU recurrence ----------------
// NEW GROUPING: 8 communication groups = (dir, batch-quarter of 32 rows),
// 16 blocks per group, each block owns a 32-wide j-slice of the hidden dim.
// With round-robin dispatch each group lands on exactly ONE XCD -> the whole
// h_{t-1} exchange (store -> flag -> poll -> load) stays inside that XCD's L2
// (~250cy hops) instead of the MALL (~1000cy hops). Placement is VERIFIED at
// runtime via HW_REG_XCC_ID + atomic claim; on any mismatch we fall back to
// MALL-scope (sc0 sc1) ops with identical algorithm -> correct under any
// dispatch (Guideline 16).
// Per-wave structure unchanged from previous version: Whh fragments resident
// in 192 VGPRs, 48 input + 48 hidden MFMAs per step, f32 master h in regs.
template<bool CLEAN>
__device__ __forceinline__ void rec_run(
    int tid, int slot, int gid,
    const unsigned short* __restrict__ xbf,
    const unsigned short* __restrict__ Wih,
    const unsigned short* __restrict__ Whh,
    const float* __restrict__ bih_f, const float* __restrict__ bih_b,
    const float* __restrict__ bhh_f, const float* __restrict__ bhh_b,
    const int* __restrict__ lengths,
    unsigned short* __restrict__ hbuf, unsigned short* __restrict__ outb,
    unsigned* __restrict__ flags,
    unsigned short (*htile)[16][20], unsigned short (*otile)[16][20]) {

  int lane = tid & 63, w = tid >> 6;
  int quad = lane >> 4, l15 = lane & 15;
  int dir = gid >> 2, bq = gid & 3;
  int rb0 = bq * 32;                 // this group's 32 batch rows
  int rt = w & 1, jh = w >> 1;       // wave tile: (row-16-tile, j-16-half)
  int j0 = slot * 32;                // block's 32-wide j slice
  int jg = j0 + jh * 16 + l15;       // this lane's output column

  const unsigned short* wih_g = Wih + (size_t)dir * (G3 * H_);
  const unsigned short* whh_g = Whh + (size_t)dir * (G3 * H_);
  const float* bih = dir ? bih_b : bih_f;
  const float* bhh = dir ? bhh_b : bhh_f;
  float b_r  = bih[jg] + bhh[jg];
  float b_z  = bih[512 + jg] + bhh[512 + jg];
  float b_in = bih[1024 + jg];
  float b_hn = bhh[1024 + jg];

  const unsigned short* wir = wih_g + (size_t)jg * H_;
  const unsigned short* wiz = wih_g + (size_t)(512 + jg) * H_;
  const unsigned short* win = wih_g + (size_t)(1024 + jg) * H_;
  const unsigned short* whr = whh_g + (size_t)jg * H_;
  const unsigned short* whz = whh_g + (size_t)(512 + jg) * H_;
  const unsigned short* whn = whh_g + (size_t)(1024 + jg) * H_;

  // hoist Whh B-fragments into registers (48 x bf16x8 = 192 VGPRs)
  bf16x8 whr_r[16], whz_r[16], whn_r[16];
  #pragma unroll
  for (int s = 0; s < 16; ++s) {
    int kb = s * 32 + quad * 8;
    whr_r[s] = *(const bf16x8*)&whr[kb];
    whz_r[s] = *(const bf16x8*)&whz[kb];
    whn_r[s] = *(const bf16x8*)&whn[kb];
  }

  int b0 = rb0 + rt * 16 + l15;      // A-frag row (global batch row)
  int L0 = lengths[b0];
  int Lg[4];
  #pragma unroll
  for (int r = 0; r < 4; ++r) Lg[r] = lengths[rb0 + rt * 16 + 4 * quad + r];
  int rsl = lane >> 2, jp = lane & 3;          // store-phase mapping (wave-local)
  int bs2 = rb0 + rt * 16 + rsl;
  int Ls2 = lengths[bs2];

  unsigned short* hb = hbuf + (size_t)dir * (B_ * H_);
  unsigned* fbase = flags + ((size_t)gid << 13);    // [gid][512][16]
  float hreg[4] = {};                // f32 master copy of own (b, j) hidden state

  #pragma unroll 1
  for (int t = 0; t < T_; ++t) {
    const unsigned short* hc = hb + (size_t)(t & 1) * (2 * B_ * H_);
    unsigned short* hnx      = hb + (size_t)((t & 1) ^ 1) * (2 * B_ * H_);

    f32x4 acc_r = {0.f,0.f,0.f,0.f}, acc_z = {0.f,0.f,0.f,0.f};
    f32x4 acc_n = {0.f,0.f,0.f,0.f}, acc_h = {0.f,0.f,0.f,0.f};

    // ---- (1) input GEMM for step t (plain cached loads; h-independent)
    int tx0 = dir ? ((t < L0) ? (L0 - 1 - t) : 0) : t;
    const unsigned short* xr0 = xbf + ((size_t)b0 * T_ + tx0) * 512;
    #pragma unroll
    for (int s = 0; s < 16; ++s) {
      int kb = s * 32 + quad * 8;
      bf16x8 ax = *(const bf16x8*)&xr0[kb];
      acc_r = MFMA16(ax, *(const bf16x8*)&wir[kb], acc_r);
      acc_z = MFMA16(ax, *(const bf16x8*)&wiz[kb], acc_z);
      acc_n = MFMA16(ax, *(const bf16x8*)&win[kb], acc_n);
    }

    if (t > 0) {
      // ---- (2) wait for this group's 16 producer flags from step t-1
      if (w == 0) {
        const unsigned* fp = fbase + ((size_t)(t - 1) << 4) + (lane & 15);
        unsigned v;
        do { v = ldflag<CLEAN>(fp); } while (__ballot(v != 0) != ~0ull);
      }
      __syncthreads();
      // ---- (3) hidden GEMM: issue all 16 x 16B h loads, then one wait
      const unsigned short* hr0 = hc + (size_t)b0 * H_;
      int4v ahq[16];
      #pragma unroll
      for (int s = 0; s < 16; ++s)
        ldh16<CLEAN>(ahq[s], hr0 + s * 32 + quad * 8);
      asm volatile("s_waitcnt vmcnt(0)" ::: "memory");
      __builtin_amdgcn_sched_barrier(0);   // rule #18: pin MFMAs after the wait
      #pragma unroll
      for (int s = 0; s < 16; ++s) {
        union { int4v i; bf16x8 b; } u; u.i = ahq[s];
        acc_r = MFMA16(u.b, whr_r[s], acc_r);
        acc_z = MFMA16(u.b, whz_r[s], acc_z);
        acc_h = MFMA16(u.b, whn_r[s], acc_h);
      }
    }

    // ---- (4) gates -> LDS tile repack (wave-local) -> u64 stores
    #pragma unroll
    for (int r = 0; r < 4; ++r) {
      bool vld = t < Lg[r];
      float rr = sigm_f(acc_r[r] + b_r);
      float zz = sigm_f(acc_z[r] + b_z);
      float nn = tanh_f(acc_n[r] + b_in + rr * (acc_h[r] + b_hn));
      float hold = hreg[r];
      float hnew = vld ? ((1.f - zz) * nn + zz * hold) : hold;
      hreg[r] = hnew;
      unsigned short hbf = f2bf(hnew);
      htile[w][4 * quad + r][l15] = hbf;
      otile[w][4 * quad + r][l15] = vld ? hbf : (unsigned short)0;
    }
    asm volatile("s_waitcnt lgkmcnt(0)" ::: "memory");
    unsigned long long hv = *(const unsigned long long*)&htile[w][rsl][jp * 4];
    unsigned long long ov = *(const unsigned long long*)&otile[w][rsl][jp * 4];
    sth64<CLEAN>(&hnx[(size_t)bs2 * H_ + j0 + jh * 16 + jp * 4], hv);
    bool vs = t < Ls2;
    int p = dir ? (vs ? (Ls2 - 1 - t) : t) : t;
    *(unsigned long long*)&outb[((size_t)bs2 * T_ + p) * 1024 + dir * 512 + j0 + jh * 16 + jp * 4] = ov;

    // ---- (5) arrive: drain h stores to the coherence point, then flag
    asm volatile("s_waitcnt vmcnt(0)" ::: "memory");
    __syncthreads();
    if (tid == 0 && t < T_ - 1)     // t=T-1 flag never polled; cells hold ctrs
      stflag<CLEAN>(fbase + ((size_t)t << 4) + slot);
  }
}

__launch_bounds__(256, 1)
__global__ void k_rec(const unsigned short* __restrict__ xbf,
                      const unsigned short* __restrict__ Wih,
                      const unsigned short* __restrict__ Whh,
                      const float* __restrict__ bih_f, const float* __restrict__ bih_b,
                      const float* __restrict__ bhh_f, const float* __restrict__ bhh_b,
                      const int* __restrict__ lengths,
                      unsigned short* __restrict__ hbuf,   // [2 buf][2 dir][128][512] bf16
                      unsigned short* __restrict__ outb,   // [65536][1024] bf16
                      unsigned* __restrict__ flags) {      // [8][512][16] + claim ctrs
  __shared__ unsigned short htile[4][16][20];
  __shared__ unsigned short otile[4][16][20];
  __shared__ int shq[4];
  int tid = threadIdx.x;

  // ---- runtime placement claim: physical XCD id -> (group, slot) ----
  if (tid == 0) {
    unsigned xcc;
    asm volatile("s_getreg_b32 %0, hwreg(HW_REG_XCC_ID)" : "=s"(xcc));
    xcc &= 7u;
    // 16 zeroed u32 cells at the tail of the flags buffer (= group7/t511 slot,
    // whose flag is never stored/polled): [0..7] per-XCD count, [8] total, [9] logical
    unsigned* ctr = flags + ((7u << 13) + (511u << 4));
    unsigned sp = __hip_atomic_fetch_add(&ctr[xcc], 1u, __ATOMIC_RELAXED, __HIP_MEMORY_SCOPE_AGENT);
    unsigned g  = __hip_atomic_fetch_add(&ctr[9], 1u, __ATOMIC_RELAXED, __HIP_MEMORY_SCOPE_AGENT);
    __hip_atomic_fetch_add(&ctr[8], 1u, __ATOMIC_RELEASE, __HIP_MEMORY_SCOPE_AGENT);
    while (__hip_atomic_load(&ctr[8], __ATOMIC_ACQUIRE, __HIP_MEMORY_SCOPE_AGENT) < 128u)
      __builtin_amdgcn_s_sleep(2);        // all 128 blocks co-resident (1/CU)
    int clean = 1;
    for (int x = 0; x < 8; ++x)
      if (__hip_atomic_load(&ctr[x], __ATOMIC_RELAXED, __HIP_MEMORY_SCOPE_AGENT) != 16u)
        clean = 0;
    shq[0] = clean ? (int)sp : (int)(g & 15u);   // slot 0..15 (j slice)
    shq[1] = clean ? (int)xcc : (int)(g >> 4);   // group 0..7 (dir, batch quarter)
    shq[2] = clean;
  }
  __syncthreads();
  int slot = shq[0], gid = shq[1], clean = shq[2];

  if (clean)
    rec_run<true >(tid, slot, gid, xbf, Wih, Whh, bih_f, bih_b, bhh_f, bhh_b,
                   lengths, hbuf, outb, flags, htile, otile);
  else
    rec_run<false>(tid, slot, gid, xbf, Wih, Whh, bih_f, bih_b, bhh_f, bhh_b,
                   lengths, hbuf, outb, flags, htile, otile);
}

// ---------------- K3: GEMM2 fused  sc4[cb] = sum_c tanh(out@Wp^T + bp) * ctx ----------------
__launch_bounds__(256)
__global__ void k_gemm2(const unsigned short* __restrict__ outbf,
                        const unsigned short* __restrict__ Wpb,
                        const float* __restrict__ bp, const float* __restrict__ ctx,
                        float* __restrict__ sc4) {     // [4][65536] partials
  __shared__ short smem[2 * 128 * 72];
  short* a_s = smem;
  short* b_s = smem + 128 * 72;
  int tid = threadIdx.x;
  int lane = tid & 63, w = tid >> 6;
  int quad = lane >> 4, l15 = lane & 15;
  int row0 = blockIdx.x * 128, col0 = blockIdx.y * 128;

  f32x4 acc[2][8];
  #pragma unroll
  for (int i = 0; i < 2; ++i)
    #pragma unroll
    for (int j = 0; j < 8; ++j) acc[i][j] = (f32x4){0.f, 0.f, 0.f, 0.f};

  for (int kt = 0; kt < 16; ++kt) {
    int k0 = kt * 64;
    __syncthreads();
    #pragma unroll
    for (int q = 0; q < 4; ++q) {
      int u = tid + 256 * q;
      int r = u >> 3, cu = u & 7;
      *(bf16x8*)&a_s[r * 72 + cu * 8] = *(const bf16x8*)&outbf[(size_t)(row0 + r) * 1024 + k0 + cu * 8];
      *(bf16x8*)&b_s[r * 72 + cu * 8] = *(const bf16x8*)&Wpb[(size_t)(col0 + r) * 1024 + k0 + cu * 8];
    }
    __syncthreads();
    #pragma unroll
    for (int kk = 0; kk < 2; ++kk) {
      int kb = kk * 32 + quad * 8;
      bf16x8 a0 = *(const bf16x8*)&a_s[(w * 32 + l15) * 72 + kb];
      bf16x8 a1 = *(const bf16x8*)&a_s[(w * 32 + 16 + l15) * 72 + kb];
      #pragma unroll
      for (int nt = 0; nt < 8; ++nt) {
        bf16x8 bb = *(const bf16x8*)&b_s[(nt * 16 + l15) * 72 + kb];
        acc[0][nt] = MFMA16(a0, bb, acc[0][nt]);
        acc[1][nt] = MFMA16(a1, bb, acc[1][nt]);
      }
    }
  }

  float rs[2][4] = {};
  #pragma unroll
  for (int mt = 0; mt < 2; ++mt) {
    #pragma unroll
    for (int nt = 0; nt < 8; ++nt) {
      int col = col0 + nt * 16 + l15;
      float bv = bp[col], cv = ctx[col];
      #pragma unroll
      for (int r = 0; r < 4; ++r) {
        float x = acc[mt][nt][r] + bv;
        rs[mt][r] += tanh_f(x) * cv;
      }
    }
  }
  #pragma unroll
  for (int mt = 0; mt < 2; ++mt) {
    #pragma unroll
    for (int r = 0; r < 4; ++r) {
      float v = rs[mt][r];
      v += __shfl_xor(v, 1); v += __shfl_xor(v, 2);
      v += __shfl_xor(v, 4); v += __shfl_xor(v, 8);
      if (l15 == 0)
        sc4[(size_t)blockIdx.y * 65536 + row0 + 32 * w + 16 * mt + 4 * quad + r] = v;
    }
  }
}

// ---------------- K4: masked softmax -> attn (output) ----------------
__launch_bounds__(64)
__global__ void k_softmax(const float* __restrict__ sc4, const int* __restrict__ lengths,
                          float* __restrict__ attn) {
  int b = blockIdx.x, lane = threadIdx.x;
  int L = lengths[b];
  float s[8]; float mx = -1e30f;
  #pragma unroll
  for (int i = 0; i < 8; ++i) {
    int t = lane + i * 64;
    int idx = b * T_ + t;
    float v = -1e30f;
    if (t < L)
      v = sc4[idx] + sc4[65536 + idx] + sc4[131072 + idx] + sc4[196608 + idx];
    s[i] = v;
    mx = fmaxf(mx, v);
  }
  #pragma unroll
  for (int o = 32; o; o >>= 1) mx = fmaxf(mx, __shfl_xor(mx, o));
  float sum = 0.f;
  #pragma unroll
  for (int i = 0; i < 8; ++i) {
    int t = lane + i * 64;
    s[i] = (t < L) ? __expf(s[i] - mx) : 0.f;
    sum += s[i];
  }
  #pragma unroll
  for (int o = 32; o; o >>= 1) sum += __shfl_xor(sum, o);
  float inv = 1.f / sum;
  #pragma unroll
  for (int i = 0; i < 8; ++i) attn[b * T_ + lane + i * 64] = s[i] * inv;
}

// ---------------- K5: attention pool + selu + classifier ----------------
__launch_bounds__(256)
__global__ void k_final(const float* __restrict__ attn, const unsigned short* __restrict__ outb,
                        const int* __restrict__ lengths,
                        const float* __restrict__ Wl, const float* __restrict__ bl,
                        float* __restrict__ logits) {
  __shared__ float red[8];
  int b = blockIdx.x, tid = threadIdx.x;
  int L = lengths[b];
  float a0 = 0.f, a1 = 0.f, a2 = 0.f, a3 = 0.f;
  for (int t = 0; t < L; ++t) {
    float a = attn[b * T_ + t];
    const unsigned short* row = outb + ((size_t)b * T_ + t) * 1024 + tid * 4;
    bf16x4 v = *(const bf16x4*)row;
    a0 += a * bf2f((unsigned short)v[0]);
    a1 += a * bf2f((unsigned short)v[1]);
    a2 += a * bf2f((unsigned short)v[2]);
    a3 += a * bf2f((unsigned short)v[3]);
  }
  const float al = 1.6732632423543772f, sc = 1.0507009873554805f;
  float s0 = sc * (a0 > 0.f ? a0 : al * (__expf(a0) - 1.f));
  float s1 = sc * (a1 > 0.f ? a1 : al * (__expf(a1) - 1.f));
  float s2 = sc * (a2 > 0.f ? a2 : al * (__expf(a2) - 1.f));
  float s3 = sc * (a3 > 0.f ? a3 : al * (__expf(a3) - 1.f));
  int d = tid * 4;
  float p0 = s0 * Wl[d] + s1 * Wl[d + 1] + s2 * Wl[d + 2] + s3 * Wl[d + 3];
  float p1 = s0 * Wl[1024 + d] + s1 * Wl[1024 + d + 1] + s2 * Wl[1024 + d + 2] + s3 * Wl[1024 + d + 3];
  #pragma unroll
  for (int o = 32; o; o >>= 1) { p0 += __shfl_xor(p0, o); p1 += __shfl_xor(p1, o); }
  if ((tid & 63) == 0) { red[(tid >> 6) * 2] = p0; red[(tid >> 6) * 2 + 1] = p1; }
  __syncthreads();
  if (tid == 0) {
    logits[b * 2]     = red[0] + red[2] + red[4] + red[6] + bl[0];
    logits[b * 2 + 1] = red[1] + red[3] + red[5] + red[7] + bl[1];
  }
}

// ---------------- launcher ----------------
extern "C" void kernel_launch(void* const* d_in, const int* in_sizes, int n_in,
                              void* d_out, int out_size, void* d_ws, size_t ws_size,
                              hipStream_t stream) {
  const int*   tokens  = (const int*)d_in[0];
  const int*   lengths = (const int*)d_in[1];
  const float* emb     = (const float*)d_in[2];
  const float* Wih_f   = (const float*)d_in[3];
  const float* Whh_f   = (const float*)d_in[4];
  const float* bih_f   = (const float*)d_in[5];
  const float* bhh_f   = (const float*)d_in[6];
  const float* Wih_b   = (const float*)d_in[7];
  const float* Whh_b   = (const float*)d_in[8];
  const float* bih_b   = (const float*)d_in[9];
  const float* bhh_b   = (const float*)d_in[10];
  const float* Wp      = (const float*)d_in[11];
  const float* bp      = (const float*)d_in[12];
  const float* ctx     = (const float*)d_in[13];
  const float* Wl      = (const float*)d_in[14];
  const float* bl      = (const float*)d_in[15];
  float* out = (float*)d_out;               // [0,256): logits, [256,65792): attn

  char* ws = (char*)d_ws;
  unsigned short* Wih  = (unsigned short*)(ws + 0);            //   3,145,728
  unsigned short* Whh  = (unsigned short*)(ws + 3145728);      //   3,145,728
  unsigned short* Wpb  = (unsigned short*)(ws + 6291456);      //   1,048,576
  unsigned short* xbf  = (unsigned short*)(ws + 7340032);      //  67,108,864
  unsigned short* outb = (unsigned short*)(ws + 74448896);     // 134,217,728
  unsigned short* hbuf = (unsigned short*)(ws + 208666624);    //     524,288
  float* sc4           = (float*)(ws + 209190912);             //   1,048,576
  unsigned* flags      = (unsigned*)(ws + 210239488);          //     262,144
  // total: 210,501,632 bytes

  k_cast<<<14336, 256, 0, stream>>>(Wih_f, Wih_b, Whh_f, Whh_b, Wp, Wih, Whh, Wpb, flags);
  k_gather<<<16384, 256, 0, stream>>>(tokens, emb, xbf);
  k_rec<<<128, 256, 0, stream>>>(xbf, Wih, Whh, bih_f, bih_b, bhh_f, bhh_b,
                                 lengths, hbuf, outb, flags);
  dim3 g2(512, 4);
  k_gemm2<<<g2, 256, 0, stream>>>(outb, Wpb, bp, ctx, sc4);
  k_softmax<<<128, 64, 0, stream>>>(sc4, lengths, out + 256);
  k_final<<<128, 256, 0, stream>>>(out + 256, outb, lengths, Wl, bl, out);
}

// Round 3
// 3716.671 us; speedup vs baseline: 1.4632x; 1.1459x over previous
//
#include <hip/hip_runtime.h>
#include <stdint.h>

#define B_  128
#define T_  512
#define H_  512
#define G3  1536

typedef __attribute__((ext_vector_type(8))) short bf16x8;
typedef __attribute__((ext_vector_type(4))) short bf16x4;
typedef __attribute__((ext_vector_type(4))) float f32x4;
typedef __attribute__((ext_vector_type(4))) int   int4v;

#define MFMA16(a,b,c) __builtin_amdgcn_mfma_f32_16x16x32_bf16((a),(b),(c),0,0,0)

__device__ __forceinline__ unsigned short f2bf(float f) {
  union { float f; unsigned u; } v; v.f = f;
  unsigned r = v.u + 0x7FFFu + ((v.u >> 16) & 1u);
  return (unsigned short)(r >> 16);
}
__device__ __forceinline__ float bf2f(unsigned short u) {
  union { unsigned u; float f; } v; v.u = ((unsigned)u) << 16; return v.f;
}
__device__ __forceinline__ float sigm_f(float x) { return 1.f / (1.f + __expf(-x)); }
__device__ __forceinline__ float tanh_f(float x) { float e = __expf(2.f * x); return 1.f - 2.f / (e + 1.f); }

// ---- scoped memory helpers -------------------------------------------------
// CLEAN (all 16 group blocks verified on ONE XCD): plain write-through stores
// + sc0 (L1-bypass) loads -> coherence point is the XCD's own L2.
// !CLEAN fallback: sc0 sc1 -> coherence at MALL; correct for any placement.
template<bool CLEAN>
__device__ __forceinline__ void sth64(unsigned short* p, unsigned long long v) {
  if constexpr (CLEAN)
    asm volatile("global_store_dwordx2 %0, %1, off" :: "v"(p), "v"(v) : "memory");
  else
    asm volatile("global_store_dwordx2 %0, %1, off sc0 sc1" :: "v"(p), "v"(v) : "memory");
}
__device__ __forceinline__ void st64p(unsigned short* p, unsigned long long v) {
  asm volatile("global_store_dwordx2 %0, %1, off" :: "v"(p), "v"(v) : "memory");
}
template<bool CLEAN>
__device__ __forceinline__ unsigned ldflag(const unsigned* p) {
  unsigned v;
  if constexpr (CLEAN)
    asm volatile("global_load_dword %0, %1, off sc0\n\ts_waitcnt vmcnt(0)"
                 : "=v"(v) : "v"(p) : "memory");
  else
    asm volatile("global_load_dword %0, %1, off sc0 sc1\n\ts_waitcnt vmcnt(0)"
                 : "=v"(v) : "v"(p) : "memory");
  return v;
}
template<bool CLEAN>
__device__ __forceinline__ void stflag(unsigned* p) {
  unsigned one = 1u;
  if constexpr (CLEAN)
    asm volatile("global_store_dword %0, %1, off" :: "v"(p), "v"(one) : "memory");
  else
    asm volatile("global_store_dword %0, %1, off sc0 sc1" :: "v"(p), "v"(one) : "memory");
}

// ---------------- K0: cast weights to bf16 + zero barrier flags ----------------
__launch_bounds__(256)
__global__ void k_cast(const float* __restrict__ Wih_f, const float* __restrict__ Wih_b,
                       const float* __restrict__ Whh_f, const float* __restrict__ Whh_b,
                       const float* __restrict__ Wp,
                       unsigned short* __restrict__ Wih, unsigned short* __restrict__ Whh,
                       unsigned short* __restrict__ Wpb, unsigned* __restrict__ flags) {
  int idx = blockIdx.x * 256 + threadIdx.x;
  if (idx < 65536) flags[idx] = 0;          // [8 grp][512 t][16 slot] flags + claim ctrs
  if (idx < 1572864) {            // Wih: [2][1536][512]
    float v = (idx < 786432) ? Wih_f[idx] : Wih_b[idx - 786432];
    Wih[idx] = f2bf(v);
  } else if (idx < 3145728) {     // Whh: [2][1536][512]
    int i2 = idx - 1572864;
    float v = (i2 < 786432) ? Whh_f[i2] : Whh_b[i2 - 786432];
    Whh[i2] = f2bf(v);
  } else if (idx < 3670016) {     // Wp: [512][1024]
    int i3 = idx - 3145728;
    Wpb[i3] = f2bf(Wp[i3]);
  }
}

// ---------------- K1: gather embedding -> x_bf [65536][512] ----------------
__launch_bounds__(256)
__global__ void k_gather(const int* __restrict__ tokens, const float* __restrict__ emb,
                         unsigned short* __restrict__ xbf) {
  int row = blockIdx.x * 4 + (threadIdx.x >> 6);
  int lane = threadIdx.x & 63;
  int tok = tokens[row];
  const float4* src = (const float4*)(emb + (size_t)tok * 512);
  float4 v0 = src[lane * 2], v1 = src[lane * 2 + 1];
  bf16x8 pk;
  pk[0] = (short)f2bf(v0.x); pk[1] = (short)f2bf(v0.y);
  pk[2] = (short)f2bf(v0.z); pk[3] = (short)f2bf(v0.w);
  pk[4] = (short)f2bf(v1.x); pk[5] = (short)f2bf(v1.y);
  pk[6] = (short)f2bf(v1.z); pk[7] = (short)f2bf(v1.w);
  *(bf16x8*)&xbf[(size_t)row * 512 + lane * 8] = pk;
}

// ---------------- K2: persistent bidirectional GRU recurrence ----------------
// Grouping/sync protocol IDENTICAL to the verified round-1 kernel:
// 8 groups = (dir, batch-quarter of 32 rows), 16 blocks/group on one XCD
// (runtime-verified via HW_REG_XCC_ID claim; MALL-scope fallback otherwise);
// block-level u32 flags [gid][512][16], wave-0 polls the 16 producer flags,
// two __syncthreads per step.
// NEW this round (perf only, no sync-structure change):
//  (a) Wih B-fragments staged ONCE into STATIC 96KB LDS, rows XOR-swizzled
//      ((j&7)<<4) -> conflict-free ds_read_b128; removes the 1.5MB/step
//      per-XCD L2 weight stream that dominated the step's serial path.
//  (b) x A-fragments prefetched one step ahead into registers via plain C++
//      loads (compiler-managed WAR/waitcnt); HBM/L2 latency hides under the
//      producer-flag wait.
template<bool CLEAN>
__device__ __forceinline__ void rec_run(
    int tid, int slot, int gid,
    const unsigned short* __restrict__ xbf,
    const unsigned short* __restrict__ Wih,
    const unsigned short* __restrict__ Whh,
    const float* __restrict__ bih_f, const float* __restrict__ bih_b,
    const float* __restrict__ bhh_f, const float* __restrict__ bhh_b,
    const int* __restrict__ lengths,
    unsigned short* __restrict__ hbuf, unsigned short* __restrict__ outb,
    unsigned* __restrict__ flags,
    unsigned short* __restrict__ wih_s,
    unsigned short (*htile)[16][20], unsigned short (*otile)[16][20]) {

  int lane = tid & 63, w = tid >> 6;
  int quad = lane >> 4, l15 = lane & 15;
  int dir = gid >> 2, bq = gid & 3;
  int rb0 = bq * 32;                 // this group's 32 batch rows
  int rt = w & 1, jh = w >> 1;       // wave tile: (row-16-half, j-16-half)
  int j0 = slot * 32;                // block's 32-wide j slice
  int bcol = jh * 16 + l15;          // 0..31 within block slice
  int jg = j0 + bcol;                // this lane's output column

  const unsigned short* wih_g = Wih + (size_t)dir * (G3 * H_);
  const unsigned short* whh_g = Whh + (size_t)dir * (G3 * H_);
  const float* bih = dir ? bih_b : bih_f;
  const float* bhh = dir ? bhh_b : bhh_f;
  float b_r  = bih[jg] + bhh[jg];
  float b_z  = bih[512 + jg] + bhh[512 + jg];
  float b_in = bih[1024 + jg];
  float b_hn = bhh[1024 + jg];

  // hoist Whh B-fragments into registers (48 x bf16x8 = 192 VGPRs)
  const unsigned short* whr = whh_g + (size_t)jg * H_;
  const unsigned short* whz = whh_g + (size_t)(512 + jg) * H_;
  const unsigned short* whn = whh_g + (size_t)(1024 + jg) * H_;
  bf16x8 whr_r[16], whz_r[16], whn_r[16];
  #pragma unroll
  for (int s = 0; s < 16; ++s) {
    int kb = s * 32 + quad * 8;
    whr_r[s] = *(const bf16x8*)&whr[kb];
    whz_r[s] = *(const bf16x8*)&whz[kb];
    whn_r[s] = *(const bf16x8*)&whn[kb];
  }

  // ---- stage Wih B-fragments into LDS, layout [3][32][512] bf16, row-swizzled:
  // row rj=(g*32+jc) stores its k-byte-chunk kc*16 at (kc*16)^((jc&7)<<4)
  // (involution; read applies the same XOR). One-time cost, conflict-free reads.
  for (int i = 0; i < 24; ++i) {
    int c = tid + 256 * i;            // 0..6143 16B-chunks (96KB)
    int kc = c & 63, rj = c >> 6;     // rj 0..95
    int jc = rj & 31, g = rj >> 5;
    int grow = g * 512 + j0 + jc;     // row in Wih[dir]: (gate g, col j0+jc)
    bf16x8 v = *(const bf16x8*)&wih_g[(size_t)grow * H_ + kc * 8];
    int dst = rj * 1024 + ((kc * 16) ^ ((jc & 7) << 4));
    *(bf16x8*)((char*)wih_s + dst) = v;
  }

  int b0 = rb0 + rt * 16 + l15;      // A-frag row (global batch row)
  int L0 = lengths[b0];
  int Lg[4];
  #pragma unroll
  for (int r = 0; r < 4; ++r) Lg[r] = lengths[rb0 + rt * 16 + 4 * quad + r];
  int rsl = lane >> 2, jp = lane & 3;          // store-phase mapping (wave-local)
  int bs2 = rb0 + rt * 16 + rsl;
  int Ls2 = lengths[bs2];

  unsigned short* hb = hbuf + (size_t)dir * (B_ * H_);
  unsigned* fbase = flags + ((size_t)gid << 13);    // [gid][512][16]

  // LDS read bases for Wih fragments (bytes)
  const char* wl = (const char*)wih_s;
  int rowR = bcol * 1024;
  int rowZ = 32768 + rowR;
  int rowN = 65536 + rowR;
  int swz = (bcol & 7) << 4;

  float hreg[4] = {};                // f32 master copy of own (b, j) hidden state

  __syncthreads();                   // Wih staging complete

  // ---- prime x prefetch for t=0 (compiler-managed loads)
  bf16x8 axn[16];
  {
    int tp = dir ? (L0 - 1) : 0;     // L0 >= 1 always
    const unsigned short* xr0 = xbf + ((size_t)b0 * T_ + tp) * 512;
    #pragma unroll
    for (int s = 0; s < 16; ++s) axn[s] = *(const bf16x8*)&xr0[s * 32 + quad * 8];
  }

  #pragma unroll 1
  for (int t = 0; t < T_; ++t) {
    const unsigned short* hc = hb + (size_t)(t & 1) * (2 * B_ * H_);
    unsigned short* hnx      = hb + (size_t)((t & 1) ^ 1) * (2 * B_ * H_);

    f32x4 acc_r = {0.f,0.f,0.f,0.f}, acc_z = {0.f,0.f,0.f,0.f};
    f32x4 acc_n = {0.f,0.f,0.f,0.f}, acc_h = {0.f,0.f,0.f,0.f};

    // ---- (1) input GEMM for step t: A from prefetched regs, B from LDS
    #pragma unroll
    for (int s = 0; s < 16; ++s) {
      int ko = (s * 64 + quad * 16) ^ swz;
      acc_r = MFMA16(axn[s], *(const bf16x8*)(wl + rowR + ko), acc_r);
      acc_z = MFMA16(axn[s], *(const bf16x8*)(wl + rowZ + ko), acc_z);
      acc_n = MFMA16(axn[s], *(const bf16x8*)(wl + rowN + ko), acc_n);
    }

    // ---- (2) prefetch x for t+1 (in flight across the poll below)
    if (t < T_ - 1) {
      int tn = t + 1;
      int txn = dir ? ((tn < L0) ? (L0 - 1 - tn) : 0) : tn;
      const unsigned short* xrn = xbf + ((size_t)b0 * T_ + txn) * 512;
      #pragma unroll
      for (int s = 0; s < 16; ++s) axn[s] = *(const bf16x8*)&xrn[s * 32 + quad * 8];
    }

    if (t > 0) {
      // ---- (3) wait for this group's 16 producer flags from step t-1
      if (w == 0) {
        const unsigned* fp = fbase + ((size_t)(t - 1) << 4) + (lane & 15);
        unsigned v;
        do { v = ldflag<CLEAN>(fp); } while (__ballot(v != 0) != ~0ull);
      }
      __syncthreads();
      // ---- (4) hidden GEMM: issue all 16 x 16B h loads, one wait, MFMAs
      const char* hq = (const char*)(hc + (size_t)b0 * H_) + quad * 16;
      int4v ah[16];
      if constexpr (CLEAN) {
#define HLX(S,OFF) asm volatile("global_load_dwordx4 %0, %1, off offset:" #OFF " sc0" : "=v"(ah[S]) : "v"(hq));
        HLX(0,0) HLX(1,64) HLX(2,128) HLX(3,192) HLX(4,256) HLX(5,320)
        HLX(6,384) HLX(7,448) HLX(8,512) HLX(9,576) HLX(10,640) HLX(11,704)
        HLX(12,768) HLX(13,832) HLX(14,896) HLX(15,960)
#undef HLX
      } else {
#define HLX(S,OFF) asm volatile("global_load_dwordx4 %0, %1, off offset:" #OFF " sc0 sc1" : "=v"(ah[S]) : "v"(hq));
        HLX(0,0) HLX(1,64) HLX(2,128) HLX(3,192) HLX(4,256) HLX(5,320)
        HLX(6,384) HLX(7,448) HLX(8,512) HLX(9,576) HLX(10,640) HLX(11,704)
        HLX(12,768) HLX(13,832) HLX(14,896) HLX(15,960)
#undef HLX
      }
      asm volatile("s_waitcnt vmcnt(0)" ::: "memory");
      __builtin_amdgcn_sched_barrier(0);   // rule #18: pin MFMAs after the wait
      #pragma unroll
      for (int s = 0; s < 16; ++s) {
        union { int4v i; bf16x8 b; } u; u.i = ah[s];
        acc_r = MFMA16(u.b, whr_r[s], acc_r);
        acc_z = MFMA16(u.b, whz_r[s], acc_z);
        acc_h = MFMA16(u.b, whn_r[s], acc_h);
      }
    }

    // ---- (5) gates -> LDS tile repack (wave-local) -> u64 stores
    #pragma unroll
    for (int r = 0; r < 4; ++r) {
      bool vld = t < Lg[r];
      float rr = sigm_f(acc_r[r] + b_r);
      float zz = sigm_f(acc_z[r] + b_z);
      float nn = tanh_f(acc_n[r] + b_in + rr * (acc_h[r] + b_hn));
      float hold = hreg[r];
      float hnew = vld ? ((1.f - zz) * nn + zz * hold) : hold;
      hreg[r] = hnew;
      unsigned short hbf = f2bf(hnew);
      htile[w][4 * quad + r][l15] = hbf;
      otile[w][4 * quad + r][l15] = vld ? hbf : (unsigned short)0;
    }
    asm volatile("s_waitcnt lgkmcnt(0)" ::: "memory");
    unsigned long long hv = *(const unsigned long long*)&htile[w][rsl][jp * 4];
    unsigned long long ov = *(const unsigned long long*)&otile[w][rsl][jp * 4];
    sth64<CLEAN>(&hnx[(size_t)bs2 * H_ + j0 + jh * 16 + jp * 4], hv);
    bool vs = t < Ls2;
    int p = dir ? (vs ? (Ls2 - 1 - t) : t) : t;
    st64p(&outb[((size_t)bs2 * T_ + p) * 1024 + dir * 512 + j0 + jh * 16 + jp * 4], ov);

    // ---- (6) arrive: drain h stores to the coherence point, then flag
    asm volatile("s_waitcnt vmcnt(0)" ::: "memory");
    __syncthreads();
    if (tid == 0 && t < T_ - 1)     // t=T-1 flag never polled; cells hold ctrs
      stflag<CLEAN>(fbase + ((size_t)t << 4) + slot);
  }
}

__launch_bounds__(256, 1)
__global__ void k_rec(const unsigned short* __restrict__ xbf,
                      const unsigned short* __restrict__ Wih,
                      const unsigned short* __restrict__ Whh,
                      const float* __restrict__ bih_f, const float* __restrict__ bih_b,
                      const float* __restrict__ bhh_f, const float* __restrict__ bhh_b,
                      const int* __restrict__ lengths,
                      unsigned short* __restrict__ hbuf,   // [2 buf][2 dir][128][512] bf16
                      unsigned short* __restrict__ outb,   // [65536][1024] bf16
                      unsigned* __restrict__ flags) {      // [8][512][16] + claim ctrs
  __shared__ unsigned short wih_s[3 * 32 * 512];     // 96KB static Wih stage
  __shared__ unsigned short htile[4][16][20];
  __shared__ unsigned short otile[4][16][20];
  __shared__ int shq[4];
  int tid = threadIdx.x;

  // ---- runtime placement claim: physical XCD id -> (group, slot) ----
  if (tid == 0) {
    unsigned xcc;
    asm volatile("s_getreg_b32 %0, hwreg(HW_REG_XCC_ID)" : "=s"(xcc));
    xcc &= 7u;
    // 16 zeroed u32 cells in the never-used [gid=7][t=511] flag row:
    // [0..7] per-XCD count, [8] total, [9] logical order
    unsigned* ctr = flags + ((7u << 13) + (511u << 4));
    unsigned sp = __hip_atomic_fetch_add(&ctr[xcc], 1u, __ATOMIC_RELAXED, __HIP_MEMORY_SCOPE_AGENT);
    unsigned g  = __hip_atomic_fetch_add(&ctr[9], 1u, __ATOMIC_RELAXED, __HIP_MEMORY_SCOPE_AGENT);
    __hip_atomic_fetch_add(&ctr[8], 1u, __ATOMIC_RELEASE, __HIP_MEMORY_SCOPE_AGENT);
    while (__hip_atomic_load(&ctr[8], __ATOMIC_ACQUIRE, __HIP_MEMORY_SCOPE_AGENT) < 128u)
      __builtin_amdgcn_s_sleep(2);        // all 128 blocks co-resident (1/CU)
    int clean = 1;
    for (int x = 0; x < 8; ++x)
      if (__hip_atomic_load(&ctr[x], __ATOMIC_RELAXED, __HIP_MEMORY_SCOPE_AGENT) != 16u)
        clean = 0;
    shq[0] = clean ? (int)sp : (int)(g & 15u);   // slot 0..15 (j slice)
    shq[1] = clean ? (int)xcc : (int)(g >> 4);   // group 0..7 (dir, batch quarter)
    shq[2] = clean;
  }
  __syncthreads();
  int slot = shq[0], gid = shq[1], clean = shq[2];

  if (clean)
    rec_run<true >(tid, slot, gid, xbf, Wih, Whh, bih_f, bih_b, bhh_f, bhh_b,
                   lengths, hbuf, outb, flags, wih_s, htile, otile);
  else
    rec_run<false>(tid, slot, gid, xbf, Wih, Whh, bih_f, bih_b, bhh_f, bhh_b,
                   lengths, hbuf, outb, flags, wih_s, htile, otile);
}

// ---------------- K3: GEMM2 fused  sc4[cb] = sum_c tanh(out@Wp^T + bp) * ctx ----------------
__launch_bounds__(256)
__global__ void k_gemm2(const unsigned short* __restrict__ outbf,
                        const unsigned short* __restrict__ Wpb,
                        const float* __restrict__ bp, const float* __restrict__ ctx,
                        float* __restrict__ sc4) {     // [4][65536] partials
  __shared__ short smem[2 * 128 * 72];
  short* a_s = smem;
  short* b_s = smem + 128 * 72;
  int tid = threadIdx.x;
  int lane = tid & 63, w = tid >> 6;
  int quad = lane >> 4, l15 = lane & 15;
  int row0 = blockIdx.x * 128, col0 = blockIdx.y * 128;

  f32x4 acc[2][8];
  #pragma unroll
  for (int i = 0; i < 2; ++i)
    #pragma unroll
    for (int j = 0; j < 8; ++j) acc[i][j] = (f32x4){0.f, 0.f, 0.f, 0.f};

  for (int kt = 0; kt < 16; ++kt) {
    int k0 = kt * 64;
    __syncthreads();
    #pragma unroll
    for (int q = 0; q < 4; ++q) {
      int u = tid + 256 * q;
      int r = u >> 3, cu = u & 7;
      *(bf16x8*)&a_s[r * 72 + cu * 8] = *(const bf16x8*)&outbf[(size_t)(row0 + r) * 1024 + k0 + cu * 8];
      *(bf16x8*)&b_s[r * 72 + cu * 8] = *(const bf16x8*)&Wpb[(size_t)(col0 + r) * 1024 + k0 + cu * 8];
    }
    __syncthreads();
    #pragma unroll
    for (int kk = 0; kk < 2; ++kk) {
      int kb = kk * 32 + quad * 8;
      bf16x8 a0 = *(const bf16x8*)&a_s[(w * 32 + l15) * 72 + kb];
      bf16x8 a1 = *(const bf16x8*)&a_s[(w * 32 + 16 + l15) * 72 + kb];
      #pragma unroll
      for (int nt = 0; nt < 8; ++nt) {
        bf16x8 bb = *(const bf16x8*)&b_s[(nt * 16 + l15) * 72 + kb];
        acc[0][nt] = MFMA16(a0, bb, acc[0][nt]);
        acc[1][nt] = MFMA16(a1, bb, acc[1][nt]);
      }
    }
  }

  float rs[2][4] = {};
  #pragma unroll
  for (int mt = 0; mt < 2; ++mt) {
    #pragma unroll
    for (int nt = 0; nt < 8; ++nt) {
      int col = col0 + nt * 16 + l15;
      float bv = bp[col], cv = ctx[col];
      #pragma unroll
      for (int r = 0; r < 4; ++r) {
        float x = acc[mt][nt][r] + bv;
        rs[mt][r] += tanh_f(x) * cv;
      }
    }
  }
  #pragma unroll
  for (int mt = 0; mt < 2; ++mt) {
    #pragma unroll
    for (int r = 0; r < 4; ++r) {
      float v = rs[mt][r];
      v += __shfl_xor(v, 1); v += __shfl_xor(v, 2);
      v += __shfl_xor(v, 4); v += __shfl_xor(v, 8);
      if (l15 == 0)
        sc4[(size_t)blockIdx.y * 65536 + row0 + 32 * w + 16 * mt + 4 * quad + r] = v;
    }
  }
}

// ---------------- K4: masked softmax -> attn (output) ----------------
__launch_bounds__(64)
__global__ void k_softmax(const float* __restrict__ sc4, const int* __restrict__ lengths,
                          float* __restrict__ attn) {
  int b = blockIdx.x, lane = threadIdx.x;
  int L = lengths[b];
  float s[8]; float mx = -1e30f;
  #pragma unroll
  for (int i = 0; i < 8; ++i) {
    int t = lane + i * 64;
    int idx = b * T_ + t;
    float v = -1e30f;
    if (t < L)
      v = sc4[idx] + sc4[65536 + idx] + sc4[131072 + idx] + sc4[196608 + idx];
    s[i] = v;
    mx = fmaxf(mx, v);
  }
  #pragma unroll
  for (int o = 32; o; o >>= 1) mx = fmaxf(mx, __shfl_xor(mx, o));
  float sum = 0.f;
  #pragma unroll
  for (int i = 0; i < 8; ++i) {
    int t = lane + i * 64;
    s[i] = (t < L) ? __expf(s[i] - mx) : 0.f;
    sum += s[i];
  }
  #pragma unroll
  for (int o = 32; o; o >>= 1) sum += __shfl_xor(sum, o);
  float inv = 1.f / sum;
  #pragma unroll
  for (int i = 0; i < 8; ++i) attn[b * T_ + lane + i * 64] = s[i] * inv;
}

// ---------------- K5: attention pool + selu + classifier ----------------
__launch_bounds__(256)
__global__ void k_final(const float* __restrict__ attn, const unsigned short* __restrict__ outb,
                        const int* __restrict__ lengths,
                        const float* __restrict__ Wl, const float* __restrict__ bl,
                        float* __restrict__ logits) {
  __shared__ float red[8];
  int b = blockIdx.x, tid = threadIdx.x;
  int L = lengths[b];
  float a0 = 0.f, a1 = 0.f, a2 = 0.f, a3 = 0.f;
  for (int t = 0; t < L; ++t) {
    float a = attn[b * T_ + t];
    const unsigned short* row = outb + ((size_t)b * T_ + t) * 1024 + tid * 4;
    bf16x4 v = *(const bf16x4*)row;
    a0 += a * bf2f((unsigned short)v[0]);
    a1 += a * bf2f((unsigned short)v[1]);
    a2 += a * bf2f((unsigned short)v[2]);
    a3 += a * bf2f((unsigned short)v[3]);
  }
  const float al = 1.6732632423543772f, sc = 1.0507009873554805f;
  float s0 = sc * (a0 > 0.f ? a0 : al * (__expf(a0) - 1.f));
  float s1 = sc * (a1 > 0.f ? a1 : al * (__expf(a1) - 1.f));
  float s2 = sc * (a2 > 0.f ? a2 : al * (__expf(a2) - 1.f));
  float s3 = sc * (a3 > 0.f ? a3 : al * (__expf(a3) - 1.f));
  int d = tid * 4;
  float p0 = s0 * Wl[d] + s1 * Wl[d + 1] + s2 * Wl[d + 2] + s3 * Wl[d + 3];
  float p1 = s0 * Wl[1024 + d] + s1 * Wl[1024 + d + 1] + s2 * Wl[1024 + d + 2] + s3 * Wl[1024 + d + 3];
  #pragma unroll
  for (int o = 32; o; o >>= 1) { p0 += __shfl_xor(p0, o); p1 += __shfl_xor(p1, o); }
  if ((tid & 63) == 0) { red[(tid >> 6) * 2] = p0; red[(tid >> 6) * 2 + 1] = p1; }
  __syncthreads();
  if (tid == 0) {
    logits[b * 2]     = red[0] + red[2] + red[4] + red[6] + bl[0];
    logits[b * 2 + 1] = red[1] + red[3] + red[5] + red[7] + bl[1];
  }
}

// ---------------- launcher ----------------
extern "C" void kernel_launch(void* const* d_in, const int* in_sizes, int n_in,
                              void* d_out, int out_size, void* d_ws, size_t ws_size,
                              hipStream_t stream) {
  const int*   tokens  = (const int*)d_in[0];
  const int*   lengths = (const int*)d_in[1];
  const float* emb     = (const float*)d_in[2];
  const float* Wih_f   = (const float*)d_in[3];
  const float* Whh_f   = (const float*)d_in[4];
  const float* bih_f   = (const float*)d_in[5];
  const float* bhh_f   = (const float*)d_in[6];
  const float* Wih_b   = (const float*)d_in[7];
  const float* Whh_b   = (const float*)d_in[8];
  const float* bih_b   = (const float*)d_in[9];
  const float* bhh_b   = (const float*)d_in[10];
  const float* Wp      = (const float*)d_in[11];
  const float* bp      = (const float*)d_in[12];
  const float* ctx     = (const float*)d_in[13];
  const float* Wl      = (const float*)d_in[14];
  const float* bl      = (const float*)d_in[15];
  float* out = (float*)d_out;               // [0,256): logits, [256,65792): attn

  char* ws = (char*)d_ws;
  unsigned short* Wih  = (unsigned short*)(ws + 0);            //   3,145,728
  unsigned short* Whh  = (unsigned short*)(ws + 3145728);      //   3,145,728
  unsigned short* Wpb  = (unsigned short*)(ws + 6291456);      //   1,048,576
  unsigned short* xbf  = (unsigned short*)(ws + 7340032);      //  67,108,864
  unsigned short* outb = (unsigned short*)(ws + 74448896);     // 134,217,728
  unsigned short* hbuf = (unsigned short*)(ws + 208666624);    //     524,288
  float* sc4           = (float*)(ws + 209190912);             //   1,048,576
  unsigned* flags      = (unsigned*)(ws + 210239488);          //     262,144
  // total: 210,501,632 bytes

  k_cast<<<14336, 256, 0, stream>>>(Wih_f, Wih_b, Whh_f, Whh_b, Wp, Wih, Whh, Wpb, flags);
  k_gather<<<16384, 256, 0, stream>>>(tokens, emb, xbf);
  k_rec<<<128, 256, 0, stream>>>(xbf, Wih, Whh, bih_f, bih_b, bhh_f, bhh_b,
                                 lengths, hbuf, outb, flags);
  dim3 g2(512, 4);
  k_gemm2<<<g2, 256, 0, stream>>>(outb, Wpb, bp, ctx, sc4);
  k_softmax<<<128, 64, 0, stream>>>(sc4, lengths, out + 256);
  k_final<<<128, 256, 0, stream>>>(out + 256, outb, lengths, Wl, bl, out);
}